// Round 4
// baseline (2485.846 us; speedup 1.0000x reference)
//
#include <hip/hip_runtime.h>
#include <math.h>

#define EPSF 1e-8f

constexpr int D_    = 128;
constexpr int NTOK  = 131072;   // 1024 * 128
constexpr int NLVL  = 4;
constexpr int NCODE = 256;
constexpr int STR   = 132;      // staging stride (floats)

// --- Kernel 1: normalize codebook rows: e_n = e / (||e|| + eps) -------------
__global__ __launch_bounds__(64) void normalize_cb(const float* __restrict__ cb,
                                                   float* __restrict__ out) {
  int row = blockIdx.x;           // 0..1023  (level*256 + code)
  int t   = threadIdx.x;          // 0..63
  float a = cb[row * D_ + t];
  float b = cb[row * D_ + t + 64];
  float ss = a * a + b * b;
#pragma unroll
  for (int m = 32; m >= 1; m >>= 1) ss += __shfl_xor(ss, m);
  float denom = sqrtf(ss) + EPSF;
  out[row * D_ + t]      = a / denom;
  out[row * D_ + t + 64] = b / denom;
}

// --- Kernel 2: main RVQ — lane-per-token, residual in 128 VGPRs -------------
// Block: 256 threads (4 waves). Each wave owns 64 tokens (one per lane).
// Codebook rows are wave-uniform -> scalar loads; inner dot = 128 v_fmac.
__global__ __launch_bounds__(256) void rvq_main(const float* __restrict__ x,
                                                const float* __restrict__ en,
                                                float* __restrict__ out_xq,
                                                float* __restrict__ out_idx,
                                                float* __restrict__ out_s,
                                                double* __restrict__ lossacc_g) {
  __shared__ float stage[64 * STR];   // 33.8 KB transpose buffer

  const int t    = threadIdx.x;
  const int lane = t & 63;
  const int w    = t >> 6;                       // wave id 0..3
  const size_t tok0 = (size_t)blockIdx.x * 256;  // block covers 256 tokens
  const size_t myTok = tok0 + (size_t)w * 64 + lane;

  float r[128];

  // ---- stage-in: coalesced x -> LDS -> per-lane registers (4 wave-chunks) --
  for (int w2 = 0; w2 < 4; ++w2) {
    __syncthreads();
    const float4* __restrict__ src = (const float4*)(x + (tok0 + (size_t)w2 * 64) * D_);
    for (int g = t; g < 64 * 32; g += 256) {
      float4 v = src[g];
      *(float4*)&stage[(g >> 5) * STR + ((g & 31) << 2)] = v;
    }
    __syncthreads();
    if (w == w2) {
#pragma unroll
      for (int d4 = 0; d4 < 32; ++d4) {
        float4 v = *(const float4*)&stage[lane * STR + d4 * 4];
        r[d4 * 4 + 0] = v.x; r[d4 * 4 + 1] = v.y;
        r[d4 * 4 + 2] = v.z; r[d4 * 4 + 3] = v.w;
      }
    }
  }

  // ---- 4 residual levels ----
  for (int lvl = 0; lvl < NLVL; ++lvl) {
    const float* __restrict__ eL = en + (size_t)lvl * NCODE * D_;

    float best = -3.0e38f;
    int   bidx = 0;

    for (int code = 0; code < NCODE; ++code) {
      const float* __restrict__ ec = eL + code * D_;   // wave-uniform address
      float s0 = 0.f, s1 = 0.f, s2 = 0.f, s3 = 0.f;
#pragma unroll
      for (int d = 0; d < D_; d += 4) {
        s0 = fmaf(ec[d + 0], r[d + 0], s0);
        s1 = fmaf(ec[d + 1], r[d + 1], s1);
        s2 = fmaf(ec[d + 2], r[d + 2], s2);
        s3 = fmaf(ec[d + 3], r[d + 3], s3);
      }
      float sv = (s0 + s1) + (s2 + s3);
      if (sv > best) { best = sv; bidx = code; }   // first-max tie-break
    }

    // best IS the projection scalar: s = r . e_n[bidx]
    float s = best;

    // gather winning code (per-lane divergent, L2-resident) and update r
    const float* __restrict__ eW = eL + bidx * D_;
    float l2 = 0.f;
#pragma unroll
    for (int d = 0; d < D_; d += 4) {
      float4 ev = *(const float4*)&eW[d];
      float n0 = r[d + 0] - s * ev.x;
      float n1 = r[d + 1] - s * ev.y;
      float n2 = r[d + 2] - s * ev.z;
      float n3 = r[d + 3] - s * ev.w;
      r[d + 0] = n0; r[d + 1] = n1; r[d + 2] = n2; r[d + 3] = n3;
      l2 += n0 * n0 + n1 * n1 + n2 * n2 + n3 * n3;
    }

    out_idx[myTok * 4 + lvl] = (float)bidx;
    out_s[myTok * 4 + lvl]   = s;

    // loss: wave-reduce then one fp64 atomic per wave per level
#pragma unroll
    for (int m = 32; m >= 1; m >>= 1) l2 += __shfl_xor(l2, m);
    if (lane == 0) atomicAdd(&lossacc_g[lvl], (double)l2);
  }

  // ---- stage-out: x_q = x - r_final (registers -> LDS -> coalesced) --------
  for (int w2 = 0; w2 < 4; ++w2) {
    __syncthreads();
    if (w == w2) {
#pragma unroll
      for (int d4 = 0; d4 < 32; ++d4) {
        float4 v;
        v.x = r[d4 * 4 + 0]; v.y = r[d4 * 4 + 1];
        v.z = r[d4 * 4 + 2]; v.w = r[d4 * 4 + 3];
        *(float4*)&stage[lane * STR + d4 * 4] = v;
      }
    }
    __syncthreads();
    const float4* __restrict__ xsrc = (const float4*)(x + (tok0 + (size_t)w2 * 64) * D_);
    float4* __restrict__ odst = (float4*)(out_xq + (tok0 + (size_t)w2 * 64) * D_);
    for (int g = t; g < 64 * 32; g += 256) {
      float4 xv = xsrc[g];
      float4 rv = *(const float4*)&stage[(g >> 5) * STR + ((g & 31) << 2)];
      float4 o;
      o.x = xv.x - rv.x; o.y = xv.y - rv.y;
      o.z = xv.z - rv.z; o.w = xv.w - rv.w;
      odst[g] = o;
    }
  }
}

// --- Kernel 3: finalize mean loss -------------------------------------------
// loss_i = (1 + BETA) * sum_i / (N*D);  mean_loss = mean over 4 levels
__global__ void finalize_loss(const double* __restrict__ lossacc_g,
                              float* __restrict__ out_loss) {
  double tot = lossacc_g[0] + lossacc_g[1] + lossacc_g[2] + lossacc_g[3];
  out_loss[0] = (float)(1.25 * tot / (4.0 * 16777216.0));
}

extern "C" void kernel_launch(void* const* d_in, const int* in_sizes, int n_in,
                              void* d_out, int out_size, void* d_ws, size_t ws_size,
                              hipStream_t stream) {
  const float* x  = (const float*)d_in[0];
  const float* cb = (const float*)d_in[1];

  float* out      = (float*)d_out;
  float* out_xq   = out;                                  // [N,128]
  float* out_loss = out + (size_t)NTOK * D_;              // [1]
  float* out_idx  = out_loss + 1;                         // [N,4] (as float)
  float* out_s    = out_idx + (size_t)NTOK * NLVL;        // [N,4]

  double* lossacc = (double*)d_ws;                        // 4 doubles
  float*  en      = (float*)((char*)d_ws + 256);          // normalized codebooks (512 KB)

  hipMemsetAsync(d_ws, 0, 256, stream);
  normalize_cb<<<NLVL * NCODE, 64, 0, stream>>>(cb, en);
  rvq_main<<<NTOK / 256, 256, 0, stream>>>(x, en, out_xq, out_idx, out_s, lossacc);
  finalize_loss<<<1, 1, 0, stream>>>(lossacc, out_loss);

  (void)in_sizes; (void)n_in; (void)out_size; (void)ws_size;
}

// Round 5
// 917.748 us; speedup vs baseline: 2.7086x; 2.7086x over previous
//
#include <hip/hip_runtime.h>
#include <math.h>

#define EPSF 1e-8f

constexpr int D_    = 128;
constexpr int NTOK  = 131072;   // 1024 * 128
constexpr int NLVL  = 4;
constexpr int NCODE = 256;
constexpr int TPB   = 256;
constexpr int TOKB  = 128;      // tokens per block: 4 waves x 32 tokens
constexpr int CHUNK = 64;       // codes staged in LDS per chunk
constexpr int STR   = 132;      // stage transpose stride (floats)

// --- Kernel 1: normalize codebook rows: e_n = e / (||e|| + eps) -------------
__global__ __launch_bounds__(64) void normalize_cb(const float* __restrict__ cb,
                                                   float* __restrict__ out) {
  int row = blockIdx.x;           // 0..1023  (level*256 + code)
  int t   = threadIdx.x;          // 0..63
  float a = cb[row * D_ + t];
  float b = cb[row * D_ + t + 64];
  float ss = a * a + b * b;
#pragma unroll
  for (int m = 32; m >= 1; m >>= 1) ss += __shfl_xor(ss, m);
  float denom = sqrtf(ss) + EPSF;
  out[row * D_ + t]      = a / denom;
  out[row * D_ + t + 64] = b / denom;
}

// --- Kernel 2: main RVQ ------------------------------------------------------
// 256 threads = 4 waves; each wave owns 32 tokens. Lane pair (l, l^32) shares
// one token: lane half = lane>>5 holds dims [half*64, half*64+64) in r[64].
// Codebook chunk (64 codes) staged in LDS; inner e-reads are wave-uniform
// broadcasts (2 addresses/wave, same-bank 2-way = free). Winning max value
// IS the projection scalar s (argmax of unnormalized r.e_n == reference's
// argmax of cosine sim, since ||r|| > 0 scaling preserves order).
__global__ __launch_bounds__(TPB) void rvq_main(const float* __restrict__ x,
                                                const float* __restrict__ en,
                                                float* __restrict__ out_xq,
                                                float* __restrict__ out_idx,
                                                float* __restrict__ out_s,
                                                double* __restrict__ lossacc_g) {
  __shared__ float smem[CHUNK * D_];   // 32 KB; doubles as stage transpose buf

  const int t    = threadIdx.x;
  const int lane = t & 63;
  const int w    = t >> 6;        // wave 0..3
  const int tl   = lane & 31;     // token-lane within wave
  const int half = lane >> 5;     // which 64-dim half this lane owns
  const size_t tok0  = (size_t)blockIdx.x * TOKB;
  const size_t myTok = tok0 + (size_t)w * 32 + tl;

  float r[64];

  // ---- stage-in: coalesced x -> LDS transpose -> per-lane registers --------
  for (int w2 = 0; w2 < 4; ++w2) {
    __syncthreads();
    const float4* __restrict__ src = (const float4*)(x + (tok0 + (size_t)w2 * 32) * D_);
    for (int g = t; g < 32 * 32; g += TPB) {          // 1024 float4
      float4 v = src[g];
      *(float4*)&smem[(g >> 5) * STR + ((g & 31) << 2)] = v;
    }
    __syncthreads();
    if (w == w2) {
#pragma unroll
      for (int d4 = 0; d4 < 16; ++d4) {
        float4 v = *(const float4*)&smem[tl * STR + half * 64 + d4 * 4];
        r[d4 * 4 + 0] = v.x; r[d4 * 4 + 1] = v.y;
        r[d4 * 4 + 2] = v.z; r[d4 * 4 + 3] = v.w;
      }
    }
  }

  // ---- 4 residual levels ----
  for (int lvl = 0; lvl < NLVL; ++lvl) {
    float best = -3.0e38f;
    int   bidx = 0;

    for (int ch = 0; ch < NCODE / CHUNK; ++ch) {
      __syncthreads();
      const float4* __restrict__ eg =
          (const float4*)(en + ((size_t)lvl * NCODE + ch * CHUNK) * D_);
      for (int g = t; g < CHUNK * D_ / 4; g += TPB)   // 2048 float4, coalesced
        ((float4*)smem)[g] = eg[g];
      __syncthreads();

      for (int code = 0; code < CHUNK; ++code) {
        const float* __restrict__ er = &smem[code * D_ + half * 64]; // uniform/half
        float s0 = 0.f, s1 = 0.f, s2 = 0.f, s3 = 0.f;
#pragma unroll
        for (int d = 0; d < 64; d += 4) {
          float4 ev = *(const float4*)&er[d];
          s0 = fmaf(ev.x, r[d + 0], s0);
          s1 = fmaf(ev.y, r[d + 1], s1);
          s2 = fmaf(ev.z, r[d + 2], s2);
          s3 = fmaf(ev.w, r[d + 3], s3);
        }
        float sv = (s0 + s1) + (s2 + s3);
        sv += __shfl_xor(sv, 32);       // combine the two D-halves
        int gc = ch * CHUNK + code;
        if (sv > best) { best = sv; bidx = gc; }  // strict > = first-max tie-break
      }
    }

    // ---- update: s = best; gather winner row from L2; r -= s*e; loss -------
    float s = best;
    const float* __restrict__ eW =
        en + ((size_t)lvl * NCODE + bidx) * D_ + half * 64;
    float l2 = 0.f;
#pragma unroll
    for (int d = 0; d < 64; d += 4) {
      float4 ev = *(const float4*)&eW[d];
      float n0 = r[d + 0] - s * ev.x;
      float n1 = r[d + 1] - s * ev.y;
      float n2 = r[d + 2] - s * ev.z;
      float n3 = r[d + 3] - s * ev.w;
      r[d + 0] = n0; r[d + 1] = n1; r[d + 2] = n2; r[d + 3] = n3;
      l2 += n0 * n0 + n1 * n1 + n2 * n2 + n3 * n3;
    }

    if (lane < 32) {
      out_idx[myTok * 4 + lvl] = (float)bidx;
      out_s[myTok * 4 + lvl]   = s;
    }

    // loss: 64-lane reduce sums both halves of all 32 tokens
#pragma unroll
    for (int m = 32; m >= 1; m >>= 1) l2 += __shfl_xor(l2, m);
    if (lane == 0) atomicAdd(&lossacc_g[lvl], (double)l2);
  }

  // ---- stage-out: x_q = x - r_final (registers -> LDS -> coalesced) --------
  for (int w2 = 0; w2 < 4; ++w2) {
    __syncthreads();
    if (w == w2) {
#pragma unroll
      for (int d4 = 0; d4 < 16; ++d4) {
        float4 v;
        v.x = r[d4 * 4 + 0]; v.y = r[d4 * 4 + 1];
        v.z = r[d4 * 4 + 2]; v.w = r[d4 * 4 + 3];
        *(float4*)&smem[tl * STR + half * 64 + d4 * 4] = v;
      }
    }
    __syncthreads();
    const float4* __restrict__ xsrc = (const float4*)(x + (tok0 + (size_t)w2 * 32) * D_);
    float4* __restrict__ odst = (float4*)(out_xq + (tok0 + (size_t)w2 * 32) * D_);
    for (int g = t; g < 32 * 32; g += TPB) {
      float4 xv = xsrc[g];
      float4 rv = *(const float4*)&smem[(g >> 5) * STR + ((g & 31) << 2)];
      float4 o;
      o.x = xv.x - rv.x; o.y = xv.y - rv.y;
      o.z = xv.z - rv.z; o.w = xv.w - rv.w;
      odst[g] = o;
    }
  }
}

// --- Kernel 3: finalize mean loss -------------------------------------------
// loss_l = (1+BETA) * S_l / (N*D);  mean over 4 levels
__global__ void finalize_loss(const double* __restrict__ lossacc_g,
                              float* __restrict__ out_loss) {
  double tot = lossacc_g[0] + lossacc_g[1] + lossacc_g[2] + lossacc_g[3];
  out_loss[0] = (float)(1.25 * tot / (4.0 * 16777216.0));
}

extern "C" void kernel_launch(void* const* d_in, const int* in_sizes, int n_in,
                              void* d_out, int out_size, void* d_ws, size_t ws_size,
                              hipStream_t stream) {
  const float* x  = (const float*)d_in[0];
  const float* cb = (const float*)d_in[1];

  float* out      = (float*)d_out;
  float* out_xq   = out;                                  // [N,128]
  float* out_loss = out + (size_t)NTOK * D_;              // [1]
  float* out_idx  = out_loss + 1;                         // [N,4] (as float)
  float* out_s    = out_idx + (size_t)NTOK * NLVL;        // [N,4]

  double* lossacc = (double*)d_ws;                        // 4 doubles
  float*  en      = (float*)((char*)d_ws + 256);          // normalized codebooks (512 KB)

  hipMemsetAsync(d_ws, 0, 256, stream);
  normalize_cb<<<NLVL * NCODE, 64, 0, stream>>>(cb, en);
  rvq_main<<<NTOK / TOKB, TPB, 0, stream>>>(x, en, out_xq, out_idx, out_s, lossacc);
  finalize_loss<<<1, 1, 0, stream>>>(lossacc, out_loss);

  (void)in_sizes; (void)n_in; (void)out_size; (void)ws_size;
}